// Round 13
// baseline (2187.777 us; speedup 1.0000x reference)
//
#include <hip/hip_runtime.h>
#include <stdint.h>

#define NB   8
#define NPTS 4096
#define CINV 64
#define MC   1024
#define KNB  64
#define NE   (NB*MC*KNB)
#define K1   67
#define CH1  64
#define CH2  64
#define CH3  128
#define NSLOT 64
#define CAP  2048
#define NTASK (NB*MC)
#define NBLK 256      // 8 FPS blocks + 248 workers
#define TBLK 256      // tail persistent blocks (1/CU guaranteed resident)
#define FTILE 16

typedef unsigned short u16;
typedef unsigned int   u32;
typedef unsigned long long u64;

static __device__ __forceinline__ float bf2f(u16 b){ return __uint_as_float(((u32)b)<<16); }
static __device__ __forceinline__ u16  f2bf(float f){
  u32 u = __float_as_uint(f);
  return (u16)((u + 0x7fffu + ((u>>16)&1u)) >> 16);
}
// Exact replica of reference distance: square each diff, sum as (x+y)+z, NO fma contraction.
static __device__ __forceinline__ float d2ref(float ax,float ay,float az,
                                              float bx,float by,float bz){
  float dx = ax-bx, dy = ay-by, dz = az-bz;
  return __fadd_rn(__fadd_rn(__fmul_rn(dx,dx), __fmul_rn(dy,dy)), __fmul_rn(dz,dz));
}
static __device__ __forceinline__ float wsum(float v){
  #pragma unroll
  for (int off = 32; off > 0; off >>= 1) v += __shfl_xor(v, off);
  return v;
}
static __device__ __forceinline__ float wmax(float v){
  #pragma unroll
  for (int off = 32; off > 0; off >>= 1) v = fmaxf(v, __shfl_xor(v, off));
  return v;
}
// One DPP max step: v = max(v, dpp_shuffle(v)). Pure VALU (no DS pipe).
template<int CTRL, int RMASK>
static __device__ __forceinline__ float dppmaxstep(float v){
  int t = __builtin_amdgcn_update_dpp(__float_as_int(v), __float_as_int(v),
                                      CTRL, RMASK, 0xF, false);
  return fmaxf(v, __int_as_float(t));
}
// Full wave64 max -> broadcast via readlane(63).
static __device__ __forceinline__ float wavemax_dpp(float v){
  v = dppmaxstep<0xB1, 0xF>(v);
  v = dppmaxstep<0x4E, 0xF>(v);
  v = dppmaxstep<0x141,0xF>(v);
  v = dppmaxstep<0x140,0xF>(v);
  v = dppmaxstep<0x142,0xA>(v);
  v = dppmaxstep<0x143,0xC>(v);
  return __int_as_float(__builtin_amdgcn_readlane(__float_as_int(v), 63));
}

// ---------------------------------------------------------------- fused front kernel
struct FpsL {
  float4 cand[16];   // (d, x, y, z), double-buffered 2x8 — coords travel with the candidate
  float4 cbuf[FTILE];
};
struct WkL {
  u64   keys[CAP];
  float Hs[64*69];
  int   nbrS[64];
  float red[8][16];
  float cxyz[3];
  int   scnt;
  int   task;
};
union FrontL { FpsL f; WkL w; };

__global__ __launch_bounds__(512) void k_front(const float* __restrict__ x,
                                               const float* __restrict__ pos,
                                               float* __restrict__ centf,
                                               float* __restrict__ out_cent,
                                               float* __restrict__ out_bsel,
                                               const float* __restrict__ W1,
                                               float* __restrict__ Spart,
                                               u16* __restrict__ y1g,
                                               int* __restrict__ cntpc,
                                               int* __restrict__ cnt_total,
                                               int* __restrict__ progress,
                                               int* __restrict__ taskctr) {
  __shared__ FrontL L;
  const int tid = threadIdx.x;

  if (blockIdx.x < NB) {
    // ============ FPS producer: 8 waves (2/SIMD), vcc-free scan, coords-in-cand resolve
    const int b = blockIdx.x;
    const int lane = tid & 63, w = tid >> 6;
    float cxr[8], cyr[8], czr[8], dist[8];
    {
      const float* pb = pos + ((size_t)b*NPTS + (size_t)tid*8)*3;
      #pragma unroll
      for (int j = 0; j < 8; ++j) {
        cxr[j] = pb[j*3+0]; cyr[j] = pb[j*3+1]; czr[j] = pb[j*3+2];
        dist[j] = 1e10f;
      }
    }
    float qx = pos[(size_t)b*NPTS*3+0];
    float qy = pos[(size_t)b*NPTS*3+1];
    float qz = pos[(size_t)b*NPTS*3+2];
    if (tid == 0) L.f.cbuf[0] = make_float4(qx, qy, qz, 0.f);
    __syncthreads();

    for (int it = 1; it < MC; ++it) {
      // ---- scan: pure min/max, vcc-free
      #pragma unroll
      for (int j = 0; j < 8; ++j) {
        float d = d2ref(cxr[j], cyr[j], czr[j], qx, qy, qz);
        dist[j] = fminf(dist[j], d);
      }
      float m01 = fmaxf(dist[0], dist[1]), m23 = fmaxf(dist[2], dist[3]);
      float m45 = fmaxf(dist[4], dist[5]), m67 = fmaxf(dist[6], dist[7]);
      float lmax = fmaxf(fmaxf(m01, m23), fmaxf(m45, m67));
      // ---- in-wave max; lowest winning lane = lowest point index
      float gmax = wavemax_dpp(lmax);
      u64 mm = __ballot(lmax == gmax);
      int wl = __ffsll((unsigned long long)mm) - 1;
      const int base = (it & 1) * 8;
      if (lane == wl) {
        // lowest-j match supplies coords (argmax-first semantics)
        float bx = cxr[7], by = cyr[7], bz = czr[7];
        #pragma unroll
        for (int j = 6; j >= 0; --j) {
          bool t = (dist[j] == gmax);
          bx = t ? cxr[j] : bx; by = t ? cyr[j] : by; bz = t ? czr[j] : bz;
        }
        L.f.cand[base + w] = make_float4(gmax, bx, by, bz);
      }
      __syncthreads();
      // ---- every wave resolves the 8 candidates (no second barrier)
      float4 cq = L.f.cand[base + (lane & 7)];
      float dm = cq.x;
      dm = dppmaxstep<0xB1, 0xF>(dm);
      dm = dppmaxstep<0x4E, 0xF>(dm);
      dm = dppmaxstep<0x141,0xF>(dm);   // max over each 8-group
      u64 m2 = __ballot(cq.x == dm);
      int wc = (__ffsll((unsigned long long)m2) - 1) & 7;  // lowest cand = lowest wave = lowest idx
      int src = (lane & ~7) | wc;
      qx = __shfl(cq.y, src); qy = __shfl(cq.z, src); qz = __shfl(cq.w, src);
      // ---- flush previous FTILE rows (centf + final outputs) + release progress
      if ((it & (FTILE-1)) == 0 && tid < FTILE) {
        int r = b*MC + (it - FTILE + tid);
        float4 cc = L.f.cbuf[tid];
        centf[r*3+0] = cc.x; centf[r*3+1] = cc.y; centf[r*3+2] = cc.z;
        out_cent[r*3+0] = cc.x; out_cent[r*3+1] = cc.y; out_cent[r*3+2] = cc.z;
        out_bsel[r] = (float)b;
        if (tid == 0)
          __hip_atomic_store(progress + b, it, __ATOMIC_RELEASE, __HIP_MEMORY_SCOPE_AGENT);
      }
      if (tid == 0) L.f.cbuf[it & (FTILE-1)] = make_float4(qx, qy, qz, 0.f);
    }
    __syncthreads();
    // final tile (rows MC-FTILE..MC-1) + progress = MC
    if (tid < FTILE) {
      int r = b*MC + (MC - FTILE + tid);
      float4 cc = L.f.cbuf[tid];
      centf[r*3+0] = cc.x; centf[r*3+1] = cc.y; centf[r*3+2] = cc.z;
      out_cent[r*3+0] = cc.x; out_cent[r*3+1] = cc.y; out_cent[r*3+2] = cc.z;
      out_bsel[r] = (float)b;
      if (tid == 0)
        __hip_atomic_store(progress + b, MC, __ATOMIC_RELEASE, __HIP_MEMORY_SCOPE_AGENT);
    }
    return;
  }

  // ============ persistent workers: ball query + stage-1 per centroid (512 thr)
  for (;;) {
    if (tid == 0) {
      int t = atomicAdd(taskctr, 1);
      L.w.task = t;
      if (t < NTASK) {
        int m = t >> 3, b = t & 7;
        while (__hip_atomic_load(progress + b, __ATOMIC_ACQUIRE, __HIP_MEMORY_SCOPE_AGENT) < m + 1)
          __builtin_amdgcn_s_sleep(8);
        int bm = b*MC + m;
        L.w.cxyz[0] = __hip_atomic_load(centf + bm*3 + 0, __ATOMIC_RELAXED, __HIP_MEMORY_SCOPE_AGENT);
        L.w.cxyz[1] = __hip_atomic_load(centf + bm*3 + 1, __ATOMIC_RELAXED, __HIP_MEMORY_SCOPE_AGENT);
        L.w.cxyz[2] = __hip_atomic_load(centf + bm*3 + 2, __ATOMIC_RELAXED, __HIP_MEMORY_SCOPE_AGENT);
      }
      L.w.scnt = 0;
    }
    __syncthreads();
    const int t = L.w.task;
    if (t >= NTASK) return;
    const int m = t >> 3, b = t & 7, bm = b*MC + m;
    const float cx = L.w.cxyz[0], cy = L.w.cxyz[1], cz = L.w.cxyz[2];

    for (int i = tid; i < NPTS; i += 512) {
      size_t o = ((size_t)b*NPTS + i)*3;
      float d = d2ref(cx, cy, cz, pos[o], pos[o+1], pos[o+2]);
      if (d <= 0.04f) {
        int p = atomicAdd(&L.w.scnt, 1);
        if (p < CAP) L.w.keys[p] = ((u64)__float_as_uint(d) << 32) | (u32)i;
      }
    }
    __syncthreads();
    int n = L.w.scnt; if (n > CAP) n = CAP;
    int P = 64; while (P < n) P <<= 1;
    for (int i = n + tid; i < P; i += 512) L.w.keys[i] = ~0ull;
    __syncthreads();
    for (int ks = 2; ks <= P; ks <<= 1)
      for (int js = ks >> 1; js > 0; js >>= 1) {
        for (int i = tid; i < P; i += 512) {
          int l = i ^ js;
          if (l > i) {
            u64 a = L.w.keys[i], c = L.w.keys[l];
            bool up = ((i & ks) == 0);
            if ((a > c) == up) { L.w.keys[i] = c; L.w.keys[l] = a; }
          }
        }
        __syncthreads();
      }
    const int c = n < KNB ? n : KNB;
    if (tid < KNB) L.w.nbrS[tid] = (tid < c) ? (int)(u32)(L.w.keys[tid] & 0xffffffffu) : 0;
    if (tid == 0) { cntpc[bm] = c; atomicAdd(cnt_total, c); }
    __syncthreads();

    {
      const int ge = tid >> 3, qb = tid & 7;
      const float4* xr = (const float4*)(x + ((size_t)(b*NPTS + L.w.nbrS[ge]))*CINV);
      #pragma unroll
      for (int rep = 0; rep < 2; ++rep) {
        int q = qb + rep*8;
        float4 v = xr[q];
        float* d = L.w.Hs + ge*69 + q*4;
        d[0] = v.x; d[1] = v.y; d[2] = v.z; d[3] = v.w;
      }
    }
    if (tid < 64) {
      int row = b*NPTS + L.w.nbrS[tid];
      L.w.Hs[tid*69+64] = pos[(size_t)row*3+0] - cx;
      L.w.Hs[tid*69+65] = pos[(size_t)row*3+1] - cy;
      L.w.Hs[tid*69+66] = pos[(size_t)row*3+2] - cz;
    }
    __syncthreads();

    const int edge = tid & 63;
    const int col  = __builtin_amdgcn_readfirstlane(tid >> 6);  // 0..7
    float acc[8];
    #pragma unroll
    for (int j = 0; j < 8; ++j) acc[j] = 0.f;
    const float* hrow = L.w.Hs + edge*69;
    const float* wcol = W1 + col*8;
    for (int k = 0; k < K1; ++k) {
      float hk = hrow[k];
      const float4* w4 = (const float4*)(wcol + k*CH1);
      float4 a = w4[0], bq = w4[1];
      acc[0] = fmaf(hk, a.x,  acc[0]); acc[1] = fmaf(hk, a.y,  acc[1]);
      acc[2] = fmaf(hk, a.z,  acc[2]); acc[3] = fmaf(hk, a.w,  acc[3]);
      acc[4] = fmaf(hk, bq.x, acc[4]); acc[5] = fmaf(hk, bq.y, acc[5]);
      acc[6] = fmaf(hk, bq.z, acc[6]); acc[7] = fmaf(hk, bq.w, acc[7]);
    }
    const bool valid = edge < c;
    #pragma unroll
    for (int j = 0; j < 8; ++j) acc[j] = valid ? acc[j] : 0.f;
    u32* dst = (u32*)(y1g + ((size_t)bm*64 + edge)*CH1 + col*8);
    #pragma unroll
    for (int j = 0; j < 4; ++j)
      dst[j] = (u32)f2bf(acc[2*j]) | ((u32)f2bf(acc[2*j+1]) << 16);
    #pragma unroll
    for (int j = 0; j < 8; ++j) {
      float s = wsum(acc[j]);
      float q = wsum(acc[j]*acc[j]);
      if (edge == 0) { L.w.red[col][j] = s; L.w.red[col][8+j] = q; }
    }
    __syncthreads();
    const int slot = bm & (NSLOT-1);
    if (tid < 64)  atomicAdd(&Spart[slot*256 + tid], L.w.red[tid>>3][tid&7]);
    else if (tid < 128) {
      int cc = tid - 64;
      atomicAdd(&Spart[slot*256 + 128 + cc], L.w.red[cc>>3][8 + (cc&7)]);
    }
  }
}

// ---------------------------------------------------------------- fused tail: s2 -> bar -> s3 -> bar -> s4
static __device__ __forceinline__ void gridbar(int* ctr, int expect) {
  __syncthreads();
  if (threadIdx.x == 0) {
    __hip_atomic_fetch_add(ctr, 1, __ATOMIC_ACQ_REL, __HIP_MEMORY_SCOPE_AGENT);
    while (__hip_atomic_load(ctr, __ATOMIC_ACQUIRE, __HIP_MEMORY_SCOPE_AGENT) < expect)
      __builtin_amdgcn_s_sleep(2);
  }
  __syncthreads();
}

template<bool STORE3>
__global__ __launch_bounds__(256) void k_tail(const u16* __restrict__ y1g,
                                              u16* __restrict__ y2g,
                                              u16* __restrict__ y3g,
                                              const float* __restrict__ W2,
                                              const float* __restrict__ W3,
                                              const float* __restrict__ g1, const float* __restrict__ b1,
                                              const float* __restrict__ g2, const float* __restrict__ b2,
                                              const float* __restrict__ g3, const float* __restrict__ b3,
                                              const int* __restrict__ cntpc,
                                              const int* __restrict__ cnt_total,
                                              const float* __restrict__ Sp1,
                                              float* __restrict__ Sp2,
                                              float* __restrict__ Sp3,
                                              int* __restrict__ bars,
                                              float* __restrict__ out0) {
  __shared__ float Hs[64*65];
  __shared__ float AB[256];     // scale [0..127], shift [128..255]
  __shared__ float red[4][64];
  __shared__ int   cntS;
  const int tid = threadIdx.x;

  auto compute_ab = [&](const float* Sp, const float* g, const float* bb, int C) {
    if (tid < C) {
      float s = 0.f, q = 0.f;
      for (int sl = 0; sl < NSLOT; ++sl) {
        s += Sp[sl*256 + tid];
        q += Sp[sl*256 + 128 + tid];
      }
      float n = (float)(*cnt_total); if (n < 1.f) n = 1.f;
      float mu  = s / n;
      float var = q / n - mu*mu; if (var < 0.f) var = 0.f;
      float inv = 1.0f / sqrtf(var + 1e-5f);
      float a = g[tid] * inv;
      AB[tid] = a; AB[128 + tid] = bb[tid] - mu*a;
    }
    __syncthreads();
  };

  // ===== stage 2: relu(bn1(y1)) @ W2  (block owns bm = blockIdx.x + k*256)
  compute_ab(Sp1, g1, b1, CH1);
  for (int bm = blockIdx.x; bm < NTASK; bm += TBLK) {
    if (tid == 0) cntS = cntpc[bm];
    {
      const u32* yt = (const u32*)y1g + (size_t)bm*2048;
      #pragma unroll
      for (int rep = 0; rep < 8; ++rep) {
        int g = rep*256 + tid;
        int e = g >> 5, c2 = g & 31, ch = c2*2;
        u32 v = yt[g];
        float lo = fmaxf(fmaf(bf2f((u16)(v & 0xffff)), AB[ch],   AB[128+ch]),   0.f);
        float hi = fmaxf(fmaf(bf2f((u16)(v >> 16)),    AB[ch+1], AB[128+ch+1]), 0.f);
        Hs[e*65 + ch] = lo; Hs[e*65 + ch + 1] = hi;
      }
    }
    __syncthreads();
    const int edge = tid & 63;
    const int col  = __builtin_amdgcn_readfirstlane(tid >> 6);
    float acc[16];
    #pragma unroll
    for (int j = 0; j < 16; ++j) acc[j] = 0.f;
    const float* hrow = Hs + edge*65;
    const float* wcol = W2 + col*16;
    for (int k = 0; k < CH1; ++k) {
      float hk = hrow[k];
      const float4* w4 = (const float4*)(wcol + k*CH2);
      #pragma unroll
      for (int q = 0; q < 4; ++q) {
        float4 wv = w4[q];
        acc[q*4+0] = fmaf(hk, wv.x, acc[q*4+0]);
        acc[q*4+1] = fmaf(hk, wv.y, acc[q*4+1]);
        acc[q*4+2] = fmaf(hk, wv.z, acc[q*4+2]);
        acc[q*4+3] = fmaf(hk, wv.w, acc[q*4+3]);
      }
    }
    const bool valid = edge < cntS;
    #pragma unroll
    for (int j = 0; j < 16; ++j) acc[j] = valid ? acc[j] : 0.f;
    u32* dst = (u32*)(y2g + ((size_t)bm*64 + edge)*CH2 + col*16);
    #pragma unroll
    for (int j = 0; j < 8; ++j)
      dst[j] = (u32)f2bf(acc[2*j]) | ((u32)f2bf(acc[2*j+1]) << 16);
    #pragma unroll
    for (int j = 0; j < 16; ++j) {
      float s = wsum(acc[j]);
      float q = wsum(acc[j]*acc[j]);
      if (edge == 0) { red[col][j] = s; red[col][16+j] = q; }
    }
    __syncthreads();
    const int slot = bm & (NSLOT-1);
    if (tid < 64)  atomicAdd(&Sp2[slot*256 + tid], red[tid>>4][tid&15]);
    else if (tid < 128) {
      int c = tid - 64;
      atomicAdd(&Sp2[slot*256 + 128 + c], red[c>>4][16 + (c&15)]);
    }
    __syncthreads();
  }
  gridbar(bars + 0, TBLK);

  // ===== stage 3: relu(bn2(y2)) @ W3
  compute_ab(Sp2, g2, b2, CH2);
  for (int bm = blockIdx.x; bm < NTASK; bm += TBLK) {
    if (tid == 0) cntS = cntpc[bm];
    {
      const u32* yt = (const u32*)y2g + (size_t)bm*2048;
      #pragma unroll
      for (int rep = 0; rep < 8; ++rep) {
        int g = rep*256 + tid;
        int e = g >> 5, c2 = g & 31, ch = c2*2;
        u32 v = yt[g];
        float lo = fmaxf(fmaf(bf2f((u16)(v & 0xffff)), AB[ch],   AB[128+ch]),   0.f);
        float hi = fmaxf(fmaf(bf2f((u16)(v >> 16)),    AB[ch+1], AB[128+ch+1]), 0.f);
        Hs[e*65 + ch] = lo; Hs[e*65 + ch + 1] = hi;
      }
    }
    __syncthreads();
    const int edge = tid & 63;
    const int col  = __builtin_amdgcn_readfirstlane(tid >> 6);
    float acc[32];
    #pragma unroll
    for (int j = 0; j < 32; ++j) acc[j] = 0.f;
    const float* hrow = Hs + edge*65;
    const float* wcol = W3 + col*32;
    for (int k = 0; k < CH2; ++k) {
      float hk = hrow[k];
      const float4* w4 = (const float4*)(wcol + k*CH3);
      #pragma unroll
      for (int q = 0; q < 8; ++q) {
        float4 wv = w4[q];
        acc[q*4+0] = fmaf(hk, wv.x, acc[q*4+0]);
        acc[q*4+1] = fmaf(hk, wv.y, acc[q*4+1]);
        acc[q*4+2] = fmaf(hk, wv.z, acc[q*4+2]);
        acc[q*4+3] = fmaf(hk, wv.w, acc[q*4+3]);
      }
    }
    const bool valid = edge < cntS;
    #pragma unroll
    for (int j = 0; j < 32; ++j) acc[j] = valid ? acc[j] : 0.f;
    if constexpr (STORE3) {
      u32* dst = (u32*)(y3g + ((size_t)bm*64 + edge)*CH3 + col*32);
      #pragma unroll
      for (int j = 0; j < 16; ++j)
        dst[j] = (u32)f2bf(acc[2*j]) | ((u32)f2bf(acc[2*j+1]) << 16);
    }
    #pragma unroll
    for (int j = 0; j < 32; ++j) {
      float s = wsum(acc[j]);
      float q = wsum(acc[j]*acc[j]);
      if (edge == 0) { red[col][j] = s; red[col][32+j] = q; }
    }
    __syncthreads();
    const int slot = bm & (NSLOT-1);
    if (tid < 128) atomicAdd(&Sp3[slot*256 + tid], red[tid>>5][tid&31]);
    else {
      int c = tid - 128;
      atomicAdd(&Sp3[slot*256 + 128 + c], red[c>>5][32 + (c&31)]);
    }
    __syncthreads();
  }
  gridbar(bars + 1, TBLK);

  // ===== stage 4: bn3 + relu + maxpool
  compute_ab(Sp3, g3, b3, CH3);
  if constexpr (STORE3) {
    // 2 centroids per block-iteration: tid>>7 selects bm, tid&127 the channel
    for (int pr = blockIdx.x; pr < NTASK/2; pr += TBLK) {
      int bm = pr*2 + (tid >> 7);
      int ch = tid & 127;
      int cnt = cntpc[bm];
      float a = AB[ch], bsh = AB[128+ch];
      const u16* yr = y3g + (size_t)bm*64*CH3 + ch;
      float mx = -1e30f;
      for (int e = 0; e < cnt; ++e)
        mx = fmaxf(mx, fmaxf(fmaf(bf2f(yr[e*CH3]), a, bsh), 0.f));
      out0[(size_t)bm*CH3 + ch] = mx;
    }
  } else {
    // fallback: recompute y3 from y2 per centroid, fused bn3+maxpool
    for (int bm = blockIdx.x; bm < NTASK; bm += TBLK) {
      __shared__ float AB2[256];
      if (tid < 128) {
        // re-derive bn2 scale/shift (AB currently holds bn3) into AB2
        float s = 0.f, q = 0.f;
        for (int sl = 0; sl < NSLOT; ++sl) {
          s += Sp2[sl*256 + tid]; q += Sp2[sl*256 + 128 + tid];
        }
        float n = (float)(*cnt_total); if (n < 1.f) n = 1.f;
        float mu = s/n, var = q/n - mu*mu; if (var < 0.f) var = 0.f;
        float inv = 1.0f/sqrtf(var + 1e-5f);
        float a2 = g2[tid]*inv;
        AB2[tid] = a2; AB2[128+tid] = b2[tid] - mu*a2;
      }
      if (tid == 0) cntS = cntpc[bm];
      __syncthreads();
      {
        const u32* yt = (const u32*)y2g + (size_t)bm*2048;
        #pragma unroll
        for (int rep = 0; rep < 8; ++rep) {
          int g = rep*256 + tid;
          int e = g >> 5, c2 = g & 31, ch = c2*2;
          u32 v = yt[g];
          float lo = fmaxf(fmaf(bf2f((u16)(v & 0xffff)), AB2[ch],   AB2[128+ch]),   0.f);
          float hi = fmaxf(fmaf(bf2f((u16)(v >> 16)),    AB2[ch+1], AB2[128+ch+1]), 0.f);
          Hs[e*65 + ch] = lo; Hs[e*65 + ch + 1] = hi;
        }
      }
      __syncthreads();
      const int edge = tid & 63;
      const int col  = __builtin_amdgcn_readfirstlane(tid >> 6);
      float acc[32];
      #pragma unroll
      for (int j = 0; j < 32; ++j) acc[j] = 0.f;
      const float* hrow = Hs + edge*65;
      const float* wcol = W3 + col*32;
      for (int k = 0; k < CH2; ++k) {
        float hk = hrow[k];
        const float4* w4 = (const float4*)(wcol + k*CH3);
        #pragma unroll
        for (int q = 0; q < 8; ++q) {
          float4 wv = w4[q];
          acc[q*4+0] = fmaf(hk, wv.x, acc[q*4+0]);
          acc[q*4+1] = fmaf(hk, wv.y, acc[q*4+1]);
          acc[q*4+2] = fmaf(hk, wv.z, acc[q*4+2]);
          acc[q*4+3] = fmaf(hk, wv.w, acc[q*4+3]);
        }
      }
      const bool valid = edge < cntS;
      #pragma unroll
      for (int j = 0; j < 32; ++j) {
        int ch = col*32 + j;
        float h = fmaxf(fmaf(acc[j], AB[ch], AB[128+ch]), 0.f);
        float mx = wmax(valid ? h : -1e30f);
        if (edge == 0) out0[(size_t)bm*CH3 + ch] = mx;
      }
      __syncthreads();
    }
  }
}

// ---------------------------------------------------------------- host
extern "C" void kernel_launch(void* const* d_in, const int* in_sizes, int n_in,
                              void* d_out, int out_size, void* d_ws, size_t ws_size,
                              hipStream_t stream) {
  (void)in_sizes; (void)n_in; (void)out_size;
  const float* x   = (const float*)d_in[0];
  const float* pos = (const float*)d_in[1];
  const float* W1  = (const float*)d_in[3];
  const float* g1  = (const float*)d_in[4];
  const float* b1  = (const float*)d_in[5];
  const float* W2  = (const float*)d_in[6];
  const float* g2  = (const float*)d_in[7];
  const float* b2  = (const float*)d_in[8];
  const float* W3  = (const float*)d_in[9];
  const float* g3  = (const float*)d_in[10];
  const float* b3  = (const float*)d_in[11];

  float* out0     = (float*)d_out;
  float* out_cent = out0 + (size_t)NB*MC*CH3;
  float* out_bsel = out_cent + (size_t)NB*MC*3;

  char* base = (char*)d_ws;
  size_t off = 0;
  auto carve = [&](size_t bytes) -> char* {
    char* p = base + off;
    off = (off + bytes + 255) & ~(size_t)255;
    return p;
  };
  float* centf = (float*)carve(sizeof(float)*NB*MC*3);
  int*   cntpc = (int*)  carve(sizeof(int)*NB*MC);
  char*  zeroblk = carve(256 + 3*NSLOT*256*sizeof(float));
  int*   cnt_total = (int*)zeroblk;
  int*   taskctr   = cnt_total + 1;
  int*   progress  = cnt_total + 2;    // 8 ints
  int*   bars      = cnt_total + 10;   // 2 ints
  float* Sp1 = (float*)(zeroblk + 256);
  float* Sp2 = Sp1 + NSLOT*256;
  float* Sp3 = Sp2 + NSLOT*256;
  u16* y1g = (u16*)carve((size_t)NE*CH1*2);
  u16* y2g = (u16*)carve((size_t)NE*CH2*2);
  u16* y3g = (u16*)carve((size_t)NE*CH3*2);
  bool have_y3 = (ws_size >= off);

  hipMemsetAsync(zeroblk, 0, 256 + 3*NSLOT*256*sizeof(float), stream);
  k_front<<<NBLK, 512, 0, stream>>>(x, pos, centf, out_cent, out_bsel,
                                    W1, Sp1, y1g, cntpc, cnt_total, progress, taskctr);
  if (have_y3)
    k_tail<true><<<TBLK, 256, 0, stream>>>(y1g, y2g, y3g, W2, W3, g1, b1, g2, b2, g3, b3,
                                           cntpc, cnt_total, Sp1, Sp2, Sp3, bars, out0);
  else
    k_tail<false><<<TBLK, 256, 0, stream>>>(y1g, y2g, y3g, W2, W3, g1, b1, g2, b2, g3, b3,
                                            cntpc, cnt_total, Sp1, Sp2, Sp3, bars, out0);
}